// Round 2
// baseline (2498.703 us; speedup 1.0000x reference)
//
#include <hip/hip_runtime.h>
#include <math.h>

#define NIMG 12
#define NSZ 256
#define HWSZ 65536
#define NBLK 768

struct GBar { unsigned cnt; unsigned gen; };

// ---------------- grid barrier (all NBLK blocks co-resident) ----------------
__device__ __forceinline__ void gsync(GBar* b)
{
  __syncthreads();
  if (threadIdx.x == 0) {
    __threadfence();
    unsigned g = __hip_atomic_load(&b->gen, __ATOMIC_RELAXED, __HIP_MEMORY_SCOPE_AGENT);
    unsigned a = __hip_atomic_fetch_add(&b->cnt, 1u, __ATOMIC_ACQ_REL, __HIP_MEMORY_SCOPE_AGENT);
    if (a == NBLK - 1u) {
      __hip_atomic_store(&b->cnt, 0u, __ATOMIC_RELAXED, __HIP_MEMORY_SCOPE_AGENT);
      __hip_atomic_store(&b->gen, g + 1u, __ATOMIC_RELEASE, __HIP_MEMORY_SCOPE_AGENT);
    } else {
      while (__hip_atomic_load(&b->gen, __ATOMIC_ACQUIRE, __HIP_MEMORY_SCOPE_AGENT) == g)
        __builtin_amdgcn_s_sleep(2);
    }
    __threadfence();
  }
  __syncthreads();
}

// ---------------- 256-point Stockham FFT, one wave per transform ----------------
__device__ __forceinline__ void fft256g(float2* A, float2* B, const float2* tw, int lane,
                                        float dir, bool active)
{
  float2* src = A;
  float2* dst = B;
  int m = 1;
#pragma unroll
  for (int s = 0; s < 8; ++s) {
    __syncthreads();
    if (active) {
#pragma unroll
      for (int h = 0; h < 2; ++h) {
        int b = lane + (h << 6);
        int k = b & (m - 1);
        int jm = b - k;
        float2 a = src[b];
        float2 c = src[b + 128];
        float2 w = tw[jm];
        float wr = w.x, wi = dir * w.y;
        float ex = a.x - c.x, ey = a.y - c.y;
        dst[2 * jm + k]     = make_float2(a.x + c.x, a.y + c.y);
        dst[2 * jm + k + m] = make_float2(ex * wr - ey * wi, ex * wi + ey * wr);
      }
    }
    float2* t = src; src = dst; dst = t;
    m <<= 1;
  }
  __syncthreads();
}
__device__ __forceinline__ void fft256(float2* A, float2* B, const float2* tw, int lane, float dir)
{
  fft256g(A, B, tw, lane, dir, true);
}

__device__ __forceinline__ void make_tw(float2* tw, int t)
{
  float s, c;
  sincospif((float)t * (1.0f / 128.0f), &s, &c);
  tw[t] = make_float2(c, s);
}

__device__ __forceinline__ double fdval(const float2* tw, int k)
{
  return 2.0 - 2.0 * (double)tw[k].x;
}

// =======================================================================================
//                                   MEGA KERNEL
// =======================================================================================
__global__ __launch_bounds__(256, 3) void k_mega(const float* __restrict__ sty,
                                                 const float* __restrict__ fkr,
                                                 const float* __restrict__ fki,
                                                 float2* __restrict__ WG,
                                                 float2* __restrict__ WF,
                                                 float2* __restrict__ FkF,
                                                 float* __restrict__ denq,
                                                 float* D1a, float* D2a,
                                                 float* D1b, float* D2b,
                                                 float* __restrict__ x49,
                                                 float* __restrict__ out,
                                                 float cmom, GBar* bar)
{
  __shared__ float2 tw[256];
  __shared__ float2 bufA[6][256];
  __shared__ float2 bufB[6][256];
  __shared__ float aL[5][256];
  __shared__ float bL[5][256];
  __shared__ float dsA[2][128];
  __shared__ double2 Ml[2][128];

  int t = threadIdx.x;
  make_tw(tw, t);
  int bid = blockIdx.x;
  int n = bid >> 6;
  int sr = bid & 63;
  int r0 = sr << 2;
  int j0 = sr << 1;
  int w = t >> 6, lane = t & 63;
  const float sc = 1.0f / 65536.0f;
  int gcw = j0 + (w & 1) + ((w >> 1) << 7);

  // ---------------- S1: row fwd FFT of STy rows r0..r0+3 -> WG ----------------
  {
    const float* src = sty + (size_t)n * HWSZ + (size_t)(r0 + w) * NSZ;
#pragma unroll
    for (int q = 0; q < 4; ++q) { int j = lane + (q << 6); bufA[w][j] = make_float2(src[j], 0.f); }
    fft256(bufA[w], bufB[w], tw, lane, -1.f);
    float2* dst = WG + (size_t)n * HWSZ + (size_t)(r0 + w) * NSZ;
#pragma unroll
    for (int q = 0; q < 4; ++q) { int j = lane + (q << 6); dst[j] = bufA[w][j]; }
  }
  gsync(bar);

  // ---------------- S2: colsetup: col FFT, FkF, denq, Fr0, col inv FFT -> WF --------
  {
    float2* WGn = WG + (size_t)n * HWSZ;
#pragma unroll
    for (int q = 0; q < 4; ++q) { int u = lane + (q << 6); bufA[w][u] = WGn[(size_t)u * NSZ + gcw]; }
    fft256(bufA[w], bufB[w], tw, lane, -1.f);
#pragma unroll
    for (int c = 0; c < 4; ++c) {
      int u = t;
      int gc = j0 + (c & 1) + ((c >> 1) << 7);
      size_t idx = (size_t)n * HWSZ + (size_t)u * NSZ + gc;
      float kr = fkr[idx], ki = fki[idx];
      float2 f = bufA[c][u];
      float2 kf = make_float2(kr * f.x + ki * f.y, kr * f.y - ki * f.x);
      FkF[idx] = kf;
      bufA[c][u] = kf;
    }
    __syncthreads();
    {
      int u0 = t & 127, p = t >> 7;
      double s1 = 0.0, s2 = 0.0;
#pragma unroll
      for (int s = 0; s < 4; ++s) {
        int u = u0 + ((s & 1) << 7);
        int c = p + ((s >> 1) << 1);
        int gc = j0 + (c & 1) + ((c >> 1) << 7);
        size_t idx = (size_t)n * HWSZ + (size_t)u * NSZ + gc;
        double kr = fkr[idx], ki = fki[idx];
        double k2 = kr * kr + ki * ki;
        double fd2 = fdval(tw, u) + fdval(tw, gc) + 1e-8;
        s1 += k2;
        s2 += k2 / fd2;
      }
      denq[(size_t)n * 16384 + (size_t)u0 * 128 + (j0 + p)] = (float)(s2 * 0.25 + 1e-6);
      dsA[p][u0] = (float)(s1 * 0.25 + 1e-6);
    }
    __syncthreads();
#pragma unroll
    for (int c = 0; c < 4; ++c) {
      int u = t;
      float d = dsA[c & 1][u & 127];
      float2 kf = bufA[c][u];
      bufA[c][u] = make_float2(kf.x / d, kf.y / d);
    }
    fft256(bufA[w], bufB[w], tw, lane, +1.f);
    float2* WFn = WF + (size_t)n * HWSZ;
#pragma unroll
    for (int q = 0; q < 4; ++q) { int u = lane + (q << 6); WFn[(size_t)u * NSZ + gcw] = bufA[w][u]; }
  }
  gsync(bar);

  // ---------------- main loop ----------------
  for (int k = 0; k < 50; ++k) {
    // ===== phase A: row inv FFT (6 rows incl halos) + shrink + G + row fwd FFT =====
    float gamp = (k >= 1) ? (float)(0.1 * exp2(-(double)(k - 1) / 50.0)) : 0.f;
    const float *D1p, *D2p; float *D1w, *D2w;
    if (k & 1) { D1p = D1a; D2p = D2a; D1w = D1b; D2w = D2b; }
    else       { D1p = D1b; D2p = D2b; D1w = D1a; D2w = D2a; }

    {
      // batch 1: rows e=0..3 (global rows r0-1 .. r0+2)
      int gr = (r0 + w - 1) & 255;
      const float2* srcW = WF + (size_t)n * HWSZ + (size_t)gr * NSZ;
#pragma unroll
      for (int q = 0; q < 4; ++q) { int j = lane + (q << 6); bufA[w][j] = srcW[j]; }
      fft256(bufA[w], bufB[w], tw, lane, +1.f);
    }
    {
      // batch 2: rows e=4,5 (global rows r0+3, r0+4) on waves 0,1
      bool act = (w < 2);
      int e = 4 + (w & 1);
      int gr = (r0 + e - 1) & 255;
      if (act) {
        const float2* srcW = WF + (size_t)n * HWSZ + (size_t)gr * NSZ;
#pragma unroll
        for (int q = 0; q < 4; ++q) { int j = lane + (q << 6); bufA[e][j] = srcW[j]; }
      }
      fft256g(bufA[e], bufB[e], tw, lane, +1.f, act);
    }
    // shrink rows e=1..5 (global rows r0..r0+4); write D for e=1..4
    for (int e = 1; e <= 5; ++e) {
      int gr = (r0 + e - 1) & 255;
      int j = t, jm1 = (j - 1) & 255;
      float xc = bufA[e][j].x * sc;
      size_t idx = (size_t)n * HWSZ + (size_t)gr * NSZ + j;
      if (k == 49 && e <= 4) x49[idx] = xc;
      float a, b;
      if (k == 0) {
        a = xc; b = xc;
      } else {
        float xl = bufA[e][jm1].x * sc;
        float xu = bufA[e - 1][j].x * sc;
        float dhr = xc - xl;
        float dvr = xc - xu;
        float d1 = D1p[idx], d2 = D2p[idx];
        float nu1 = dhr + d1, nu2 = dvr + d2;
        float nu = sqrtf(nu1 * nu1 + nu2 * nu2 + 1e-8f);
        float A = fmaxf(0.f, nu - gamp) + 1e-8f;
        A = A / (A + gamp);
        float u1 = A * nu1, u2 = A * nu2;
        float d1v = d1 + dhr - u1;
        float d2v = d2 + dvr - u2;
        if (e <= 4) { D1w[idx] = d1v; D2w[idx] = d2v; }
        a = u1 - d1v; b = u2 - d2v;
      }
      aL[e - 1][j] = a;
      bL[e - 1][j] = b;
    }
    __syncthreads();
    // G rows r0..r0+3 + fwd FFT -> WG
    {
#pragma unroll
      for (int q = 0; q < 4; ++q) {
        int j = lane + (q << 6);
        int jp1 = (j + 1) & 255;
        float g = aL[w][j] - aL[w][jp1] + bL[w][j] - bL[w + 1][j];
        bufA[w][j] = make_float2(g, 0.f);
      }
      fft256(bufA[w], bufB[w], tw, lane, -1.f);
      float2* dst = WG + (size_t)n * HWSZ + (size_t)(r0 + w) * NSZ;
#pragma unroll
      for (int q = 0; q < 4; ++q) { int j = lane + (q << 6); dst[j] = bufA[w][j]; }
    }
    gsync(bar);

    // ===== phase B: col fwd FFT + freq pointwise + col inv FFT : WG -> WF =====
    {
      float2* WGn = WG + (size_t)n * HWSZ;
#pragma unroll
      for (int q = 0; q < 4; ++q) { int u = lane + (q << 6); bufA[w][u] = WGn[(size_t)u * NSZ + gcw]; }
      fft256(bufA[w], bufB[w], tw, lane, -1.f);
#pragma unroll
      for (int c = 0; c < 4; ++c) {
        int u = t;
        int gc = j0 + (c & 1) + ((c >> 1) << 7);
        size_t idx = (size_t)n * HWSZ + (size_t)u * NSZ + gc;
        float2 kf = FkF[idx];
        float2 fg = bufA[c][u];
        bufA[c][u] = make_float2(kf.x + 1e-6f * fg.x, kf.y + 1e-6f * fg.y);
      }
      __syncthreads();
      {
        int u0 = t & 127, p = t >> 7;
        double sx = 0.0, sy = 0.0;
#pragma unroll
        for (int s = 0; s < 4; ++s) {
          int u = u0 + ((s & 1) << 7);
          int c = p + ((s >> 1) << 1);
          int gc = j0 + (c & 1) + ((c >> 1) << 7);
          size_t idx = (size_t)n * HWSZ + (size_t)u * NSZ + gc;
          float2 f1 = bufA[c][u];
          double kr = fkr[idx], ki = fki[idx];
          double fd2 = fdval(tw, u) + fdval(tw, gc) + 1e-8;
          sx += (kr * (double)f1.x - ki * (double)f1.y) / fd2;
          sy += (kr * (double)f1.y + ki * (double)f1.x) / fd2;
        }
        Ml[p][u0] = make_double2(sx * 0.25, sy * 0.25);
      }
      __syncthreads();
#pragma unroll
      for (int c = 0; c < 4; ++c) {
        int u = t;
        int gc = j0 + (c & 1) + ((c >> 1) << 7);
        size_t idx = (size_t)n * HWSZ + (size_t)u * NSZ + gc;
        float2 f1 = bufA[c][u];
        double2 m = Ml[c & 1][u & 127];
        double den = (double)denq[(size_t)n * 16384 + (size_t)(u & 127) * 128 + (j0 + (c & 1))];
        double kr = fkr[idx], ki = fki[idx];
        double px = (kr * m.x + ki * m.y) / den;
        double py = (kr * m.y - ki * m.x) / den;
        double fd2 = fdval(tw, u) + fdval(tw, gc) + 1e-8;
        double s2 = 1.0 / (1e-6 * fd2);
        bufA[c][u] = make_float2((float)(((double)f1.x - px) * s2),
                                 (float)(((double)f1.y - py) * s2));
      }
      fft256(bufA[w], bufB[w], tw, lane, +1.f);
      float2* WFn = WF + (size_t)n * HWSZ;
#pragma unroll
      for (int q = 0; q < 4; ++q) { int u = lane + (q << 6); WFn[(size_t)u * NSZ + gcw] = bufA[w][u]; }
    }
    gsync(bar);
  }

  // ---------------- C: final row inv FFT + momentum -> out ----------------
  {
    const float2* srcW = WF + (size_t)n * HWSZ + (size_t)(r0 + w) * NSZ;
#pragma unroll
    for (int q = 0; q < 4; ++q) { int j = lane + (q << 6); bufA[w][j] = srcW[j]; }
    fft256(bufA[w], bufB[w], tw, lane, +1.f);
    size_t base = (size_t)n * HWSZ + (size_t)(r0 + w) * NSZ;
#pragma unroll
    for (int q = 0; q < 4; ++q) {
      int j = lane + (q << 6);
      float v = bufA[w][j].x * sc;
      out[base + j] = v + cmom * (v - x49[base + j]);
    }
  }
}

// =======================================================================================
//                     FALLBACK: round-0 multi-kernel path (proven correct)
// =======================================================================================
__global__ __launch_bounds__(256) void k_rowfwd_sty(const float* __restrict__ sty,
                                                    float2* __restrict__ Wb)
{
  __shared__ float2 tw[256];
  __shared__ float2 bufA[4][256];
  __shared__ float2 bufB[4][256];
  int t = threadIdx.x;
  make_tw(tw, t);
  int n = blockIdx.x >> 6;
  int r0 = (blockIdx.x & 63) << 2;
  int w = t >> 6, lane = t & 63;
  const float* src = sty + (size_t)n * HWSZ + (size_t)(r0 + w) * NSZ;
#pragma unroll
  for (int q = 0; q < 4; ++q) { int j = lane + (q << 6); bufA[w][j] = make_float2(src[j], 0.f); }
  fft256(bufA[w], bufB[w], tw, lane, -1.f);
  float2* dst = Wb + (size_t)n * HWSZ + (size_t)(r0 + w) * NSZ;
#pragma unroll
  for (int q = 0; q < 4; ++q) { int j = lane + (q << 6); dst[j] = bufA[w][j]; }
}

__global__ __launch_bounds__(256) void k_colsetup(float2* __restrict__ Wb,
                                                  float2* __restrict__ FkF,
                                                  const float* __restrict__ fkr,
                                                  const float* __restrict__ fki,
                                                  float* __restrict__ denq)
{
  __shared__ float2 tw[256];
  __shared__ float2 bufA[4][256];
  __shared__ float2 bufB[4][256];
  __shared__ float dsA[2][128];
  int t = threadIdx.x;
  make_tw(tw, t);
  int n = blockIdx.x >> 6;
  int j0 = (blockIdx.x & 63) << 1;
  int w = t >> 6, lane = t & 63;
  int gcw = j0 + (w & 1) + ((w >> 1) << 7);
  float2* Wn = Wb + (size_t)n * HWSZ;
#pragma unroll
  for (int q = 0; q < 4; ++q) { int u = lane + (q << 6); bufA[w][u] = Wn[(size_t)u * NSZ + gcw]; }
  fft256(bufA[w], bufB[w], tw, lane, -1.f);
#pragma unroll
  for (int c = 0; c < 4; ++c) {
    int u = t;
    int gc = j0 + (c & 1) + ((c >> 1) << 7);
    size_t idx = (size_t)n * HWSZ + (size_t)u * NSZ + gc;
    float kr = fkr[idx], ki = fki[idx];
    float2 f = bufA[c][u];
    float2 kf = make_float2(kr * f.x + ki * f.y, kr * f.y - ki * f.x);
    FkF[idx] = kf;
    bufA[c][u] = kf;
  }
  __syncthreads();
  {
    int u0 = t & 127, p = t >> 7;
    double s1 = 0.0, s2 = 0.0;
#pragma unroll
    for (int s = 0; s < 4; ++s) {
      int u = u0 + ((s & 1) << 7);
      int c = p + ((s >> 1) << 1);
      int gc = j0 + (c & 1) + ((c >> 1) << 7);
      size_t idx = (size_t)n * HWSZ + (size_t)u * NSZ + gc;
      double kr = fkr[idx], ki = fki[idx];
      double k2 = kr * kr + ki * ki;
      double fd2 = fdval(tw, u) + fdval(tw, gc) + 1e-8;
      s1 += k2;
      s2 += k2 / fd2;
    }
    denq[(size_t)n * 16384 + (size_t)u0 * 128 + (j0 + p)] = (float)(s2 * 0.25 + 1e-6);
    dsA[p][u0] = (float)(s1 * 0.25 + 1e-6);
  }
  __syncthreads();
#pragma unroll
  for (int c = 0; c < 4; ++c) {
    int u = t;
    float d = dsA[c & 1][u & 127];
    float2 kf = bufA[c][u];
    bufA[c][u] = make_float2(kf.x / d, kf.y / d);
  }
  fft256(bufA[w], bufB[w], tw, lane, +1.f);
#pragma unroll
  for (int q = 0; q < 4; ++q) { int u = lane + (q << 6); Wn[(size_t)u * NSZ + gcw] = bufA[w][u]; }
}

__global__ __launch_bounds__(256) void k_spatial_rowfwd(const float* __restrict__ x,
                                                        const float* __restrict__ D1p,
                                                        const float* __restrict__ D2p,
                                                        float* __restrict__ D1n,
                                                        float* __restrict__ D2n,
                                                        float2* __restrict__ Wb,
                                                        float gamp, int firstIter)
{
  __shared__ float2 tw[256];
  __shared__ float aL[5][256];
  __shared__ float bL[5][256];
  __shared__ float2 bufA[4][256];
  __shared__ float2 bufB[4][256];
  int t = threadIdx.x;
  make_tw(tw, t);
  int n = blockIdx.x >> 6;
  int r0 = (blockIdx.x & 63) << 2;
  const float* xn = x + (size_t)n * HWSZ;
  for (int rr = 0; rr < 5; ++rr) {
    int i = (r0 + rr) & 255;
    int im1 = (i - 1) & 255;
    int j = t;
    int jm1 = (j - 1) & 255;
    float xc = xn[(size_t)i * NSZ + j];
    float a, b;
    if (firstIter) {
      a = xc; b = xc;
    } else {
      float dhr = xc - xn[(size_t)i * NSZ + jm1];
      float dvr = xc - xn[(size_t)im1 * NSZ + j];
      size_t idx = (size_t)n * HWSZ + (size_t)i * NSZ + j;
      float d1 = D1p[idx], d2 = D2p[idx];
      float nu1 = dhr + d1, nu2 = dvr + d2;
      float nu = sqrtf(nu1 * nu1 + nu2 * nu2 + 1e-8f);
      float A = fmaxf(0.f, nu - gamp) + 1e-8f;
      A = A / (A + gamp);
      float u1 = A * nu1, u2 = A * nu2;
      float d1v = d1 + dhr - u1;
      float d2v = d2 + dvr - u2;
      if (rr < 4) { D1n[idx] = d1v; D2n[idx] = d2v; }
      a = u1 - d1v; b = u2 - d2v;
    }
    aL[rr][j] = a;
    bL[rr][j] = b;
  }
  __syncthreads();
  int w = t >> 6, lane = t & 63;
#pragma unroll
  for (int q = 0; q < 4; ++q) {
    int j = lane + (q << 6);
    int jp1 = (j + 1) & 255;
    float g = aL[w][j] - aL[w][jp1] + bL[w][j] - bL[w + 1][j];
    bufA[w][j] = make_float2(g, 0.f);
  }
  fft256(bufA[w], bufB[w], tw, lane, -1.f);
  float2* dst = Wb + (size_t)n * HWSZ + (size_t)(r0 + w) * NSZ;
#pragma unroll
  for (int q = 0; q < 4; ++q) { int j = lane + (q << 6); dst[j] = bufA[w][j]; }
}

__global__ __launch_bounds__(256) void k_colphase(float2* __restrict__ Wb,
                                                  const float2* __restrict__ FkF,
                                                  const float* __restrict__ fkr,
                                                  const float* __restrict__ fki,
                                                  const float* __restrict__ denq)
{
  __shared__ float2 tw[256];
  __shared__ float2 bufA[4][256];
  __shared__ float2 bufB[4][256];
  __shared__ double2 Ml[2][128];
  int t = threadIdx.x;
  make_tw(tw, t);
  int n = blockIdx.x >> 6;
  int j0 = (blockIdx.x & 63) << 1;
  int w = t >> 6, lane = t & 63;
  int gcw = j0 + (w & 1) + ((w >> 1) << 7);
  float2* Wn = Wb + (size_t)n * HWSZ;
#pragma unroll
  for (int q = 0; q < 4; ++q) { int u = lane + (q << 6); bufA[w][u] = Wn[(size_t)u * NSZ + gcw]; }
  fft256(bufA[w], bufB[w], tw, lane, -1.f);
#pragma unroll
  for (int c = 0; c < 4; ++c) {
    int u = t;
    int gc = j0 + (c & 1) + ((c >> 1) << 7);
    size_t idx = (size_t)n * HWSZ + (size_t)u * NSZ + gc;
    float2 kf = FkF[idx];
    float2 fg = bufA[c][u];
    bufA[c][u] = make_float2(kf.x + 1e-6f * fg.x, kf.y + 1e-6f * fg.y);
  }
  __syncthreads();
  {
    int u0 = t & 127, p = t >> 7;
    double sx = 0.0, sy = 0.0;
#pragma unroll
    for (int s = 0; s < 4; ++s) {
      int u = u0 + ((s & 1) << 7);
      int c = p + ((s >> 1) << 1);
      int gc = j0 + (c & 1) + ((c >> 1) << 7);
      size_t idx = (size_t)n * HWSZ + (size_t)u * NSZ + gc;
      float2 f1 = bufA[c][u];
      double kr = fkr[idx], ki = fki[idx];
      double fd2 = fdval(tw, u) + fdval(tw, gc) + 1e-8;
      sx += (kr * (double)f1.x - ki * (double)f1.y) / fd2;
      sy += (kr * (double)f1.y + ki * (double)f1.x) / fd2;
    }
    Ml[p][u0] = make_double2(sx * 0.25, sy * 0.25);
  }
  __syncthreads();
#pragma unroll
  for (int c = 0; c < 4; ++c) {
    int u = t;
    int gc = j0 + (c & 1) + ((c >> 1) << 7);
    size_t idx = (size_t)n * HWSZ + (size_t)u * NSZ + gc;
    float2 f1 = bufA[c][u];
    double2 m = Ml[c & 1][u & 127];
    double den = (double)denq[(size_t)n * 16384 + (size_t)(u & 127) * 128 + (j0 + (c & 1))];
    double kr = fkr[idx], ki = fki[idx];
    double px = (kr * m.x + ki * m.y) / den;
    double py = (kr * m.y - ki * m.x) / den;
    double fd2 = fdval(tw, u) + fdval(tw, gc) + 1e-8;
    double s2 = 1.0 / (1e-6 * fd2);
    bufA[c][u] = make_float2((float)(((double)f1.x - px) * s2),
                             (float)(((double)f1.y - py) * s2));
  }
  fft256(bufA[w], bufB[w], tw, lane, +1.f);
#pragma unroll
  for (int q = 0; q < 4; ++q) { int u = lane + (q << 6); Wn[(size_t)u * NSZ + gcw] = bufA[w][u]; }
}

__global__ __launch_bounds__(256) void k_rowinv(const float2* __restrict__ Wb,
                                                float* __restrict__ xout,
                                                const float* __restrict__ xold,
                                                float* __restrict__ pred,
                                                float cmom, int isLast)
{
  __shared__ float2 tw[256];
  __shared__ float2 bufA[4][256];
  __shared__ float2 bufB[4][256];
  int t = threadIdx.x;
  make_tw(tw, t);
  int n = blockIdx.x >> 6;
  int r0 = (blockIdx.x & 63) << 2;
  int w = t >> 6, lane = t & 63;
  const float2* src = Wb + (size_t)n * HWSZ + (size_t)(r0 + w) * NSZ;
#pragma unroll
  for (int q = 0; q < 4; ++q) { int j = lane + (q << 6); bufA[w][j] = src[j]; }
  fft256(bufA[w], bufB[w], tw, lane, +1.f);
  size_t base = (size_t)n * HWSZ + (size_t)(r0 + w) * NSZ;
#pragma unroll
  for (int q = 0; q < 4; ++q) {
    int j = lane + (q << 6);
    float v = bufA[w][j].x * (1.0f / 65536.0f);
    xout[base + j] = v;
    if (isLast) pred[base + j] = v + cmom * (v - xold[base + j]);
  }
}

// =======================================================================================
extern "C" void kernel_launch(void* const* d_in, const int* in_sizes, int n_in,
                              void* d_out, int out_size, void* d_ws, size_t ws_size,
                              hipStream_t stream)
{
  (void)in_sizes; (void)n_in; (void)out_size; (void)ws_size;
  const float* STy = (const float*)d_in[0];
  const float* fkr = (const float*)d_in[1];
  const float* fki = (const float*)d_in[2];
  float* out = (float*)d_out;

  char* p = (char*)d_ws;
  const size_t cplx = (size_t)NIMG * HWSZ * sizeof(float2);
  const size_t realb = (size_t)NIMG * HWSZ * sizeof(float);
  float2* WG  = (float2*)p; p += cplx;
  float2* WF  = (float2*)p; p += cplx;
  float2* FkF = (float2*)p; p += cplx;
  float* denq = (float*)p;  p += (size_t)NIMG * 16384 * sizeof(float);
  float* D1a = (float*)p;   p += realb;
  float* D2a = (float*)p;   p += realb;
  float* D1b = (float*)p;   p += realb;
  float* D2b = (float*)p;   p += realb;
  float* xA  = (float*)p;   p += realb;   // mega: x49 ; fallback: x0
  float* xB  = (float*)p;   p += realb;   // fallback: x1
  GBar* bar  = (GBar*)p;    p += 64;

  // host-side FISTA t sequence -> final momentum coefficient
  double t_old = 1.0, cm = 0.0;
  for (int k = 0; k < 50; ++k) {
    double t_new = (1.0 + sqrt(1.0 + 4.0 * t_old * t_old)) * 0.5;
    if (k == 49) cm = (t_old - 1.0) / t_new;
    t_old = t_new;
  }

  int maxb = 0;
  hipError_t oe = hipOccupancyMaxActiveBlocksPerMultiprocessor(&maxb, k_mega, 256, 0);
  bool coop = (oe == hipSuccess && maxb >= 3);

  hipMemsetAsync(D1a, 0, 2 * realb, stream);   // D^0 = 0

  dim3 grid(NBLK), blk(256);
  if (coop) {
    hipMemsetAsync(bar, 0, sizeof(GBar), stream);
    k_mega<<<grid, blk, 0, stream>>>(STy, fkr, fki, WG, WF, FkF, denq,
                                     D1a, D2a, D1b, D2b, xA, out, (float)cm, bar);
  } else {
    // proven round-0 path
    float2* Wb = WG;
    float* x0 = xA; float* x1 = xB;
    k_rowfwd_sty<<<grid, blk, 0, stream>>>(STy, Wb);
    k_colsetup<<<grid, blk, 0, stream>>>(Wb, FkF, fkr, fki, denq);
    k_rowinv<<<grid, blk, 0, stream>>>(Wb, x0, x0, out, 0.f, 0);
    double to = 1.0;
    for (int k = 0; k < 50; ++k) {
      float gamp = (k >= 1) ? (float)(0.1 * exp2(-(double)(k - 1) / 50.0)) : 0.f;
      const float* xk = (k & 1) ? x1 : x0;
      float* xn = (k & 1) ? x0 : x1;
      const float* D1p = (k & 1) ? D1a : D1b;
      const float* D2p = (k & 1) ? D2a : D2b;
      float* D1w = (k & 1) ? D1b : D1a;
      float* D2w = (k & 1) ? D2b : D2a;
      k_spatial_rowfwd<<<grid, blk, 0, stream>>>(xk, D1p, D2p, D1w, D2w, Wb, gamp, (k == 0) ? 1 : 0);
      k_colphase<<<grid, blk, 0, stream>>>(Wb, FkF, fkr, fki, denq);
      double tn = (1.0 + sqrt(1.0 + 4.0 * to * to)) * 0.5;
      int isLast = (k == 49) ? 1 : 0;
      float cmom = (float)((to - 1.0) / tn);
      k_rowinv<<<grid, blk, 0, stream>>>(Wb, xn, xk, out, isLast ? cmom : 0.f, isLast);
      to = tn;
    }
  }
}

// Round 3
// 2485.193 us; speedup vs baseline: 1.0054x; 1.0054x over previous
//
#include <hip/hip_runtime.h>
#include <math.h>

#define NIMG 12
#define NSZ 256
#define HWSZ 65536
#define NBLK 768

// ---------------- per-image flag barrier: 64 blocks, no RMW ----------------
// flags[n*64 + b] holds the last generation block b of image n has reached.
// Wave 0's 64 lanes poll all 64 flags (one coalesced 256B load per poll).
__device__ __forceinline__ void isync(unsigned* flags, int base, int sr, unsigned gen)
{
  __syncthreads();
  int t = threadIdx.x;
  if (t < 64) {
    if (t == 0) {
      __builtin_amdgcn_fence(__ATOMIC_RELEASE, "agent");
      __hip_atomic_store(&flags[base + sr], gen, __ATOMIC_RELAXED, __HIP_MEMORY_SCOPE_AGENT);
    }
    unsigned v;
    do {
      v = __hip_atomic_load(&flags[base + t], __ATOMIC_RELAXED, __HIP_MEMORY_SCOPE_AGENT);
    } while (__any(v < gen));
    __builtin_amdgcn_fence(__ATOMIC_ACQUIRE, "agent");
  }
  __syncthreads();
}

// ---------------- 256-point Stockham FFT, one wave per transform ----------------
__device__ __forceinline__ void fft256g(float2* A, float2* B, const float2* tw, int lane,
                                        float dir, bool active)
{
  float2* src = A;
  float2* dst = B;
  int m = 1;
#pragma unroll
  for (int s = 0; s < 8; ++s) {
    __syncthreads();
    if (active) {
#pragma unroll
      for (int h = 0; h < 2; ++h) {
        int b = lane + (h << 6);
        int k = b & (m - 1);
        int jm = b - k;
        float2 a = src[b];
        float2 c = src[b + 128];
        float2 w = tw[jm];
        float wr = w.x, wi = dir * w.y;
        float ex = a.x - c.x, ey = a.y - c.y;
        dst[2 * jm + k]     = make_float2(a.x + c.x, a.y + c.y);
        dst[2 * jm + k + m] = make_float2(ex * wr - ey * wi, ex * wi + ey * wr);
      }
    }
    float2* t = src; src = dst; dst = t;
    m <<= 1;
  }
  __syncthreads();
}
__device__ __forceinline__ void fft256(float2* A, float2* B, const float2* tw, int lane, float dir)
{
  fft256g(A, B, tw, lane, dir, true);
}

__device__ __forceinline__ void make_tw(float2* tw, int t)
{
  float s, c;
  sincospif((float)t * (1.0f / 128.0f), &s, &c);
  tw[t] = make_float2(c, s);
}

__device__ __forceinline__ double fdval(const float2* tw, int k)
{
  return 2.0 - 2.0 * (double)tw[k].x;
}

// =======================================================================================
//                                   MEGA KERNEL
// =======================================================================================
__global__ __launch_bounds__(256, 3) void k_mega(const float* __restrict__ sty,
                                                 const float* __restrict__ fkr,
                                                 const float* __restrict__ fki,
                                                 float2* __restrict__ WG,
                                                 float2* __restrict__ WF,
                                                 float2* __restrict__ FkF,
                                                 float* __restrict__ denq,
                                                 float* D1a, float* D2a,
                                                 float* D1b, float* D2b,
                                                 float* __restrict__ x49,
                                                 float* __restrict__ out,
                                                 float cmom, unsigned* flags)
{
  __shared__ float2 tw[256];
  __shared__ float2 bufA[6][256];
  __shared__ float2 bufB[6][256];
  __shared__ float aL[5][256];
  __shared__ float bL[5][256];
  __shared__ float dsA[2][128];
  __shared__ double2 Ml[2][128];

  int t = threadIdx.x;
  make_tw(tw, t);
  int bid = blockIdx.x;
  int n = bid >> 6;
  int sr = bid & 63;
  int fbase = n << 6;
  int r0 = sr << 2;
  int j0 = sr << 1;
  int w = t >> 6, lane = t & 63;
  const float sc = 1.0f / 65536.0f;
  int gcw = j0 + (w & 1) + ((w >> 1) << 7);
  unsigned gen = 0;

  // ---------------- S1: row fwd FFT of STy rows r0..r0+3 -> WG ----------------
  {
    const float* src = sty + (size_t)n * HWSZ + (size_t)(r0 + w) * NSZ;
#pragma unroll
    for (int q = 0; q < 4; ++q) { int j = lane + (q << 6); bufA[w][j] = make_float2(src[j], 0.f); }
    fft256(bufA[w], bufB[w], tw, lane, -1.f);
    float2* dst = WG + (size_t)n * HWSZ + (size_t)(r0 + w) * NSZ;
#pragma unroll
    for (int q = 0; q < 4; ++q) { int j = lane + (q << 6); dst[j] = bufA[w][j]; }
  }
  isync(flags, fbase, sr, ++gen);

  // ---------------- S2: colsetup: col FFT, FkF, denq, Fr0, col inv FFT -> WF --------
  {
    float2* WGn = WG + (size_t)n * HWSZ;
#pragma unroll
    for (int q = 0; q < 4; ++q) { int u = lane + (q << 6); bufA[w][u] = WGn[(size_t)u * NSZ + gcw]; }
    fft256(bufA[w], bufB[w], tw, lane, -1.f);
#pragma unroll
    for (int c = 0; c < 4; ++c) {
      int u = t;
      int gc = j0 + (c & 1) + ((c >> 1) << 7);
      size_t idx = (size_t)n * HWSZ + (size_t)u * NSZ + gc;
      float kr = fkr[idx], ki = fki[idx];
      float2 f = bufA[c][u];
      float2 kf = make_float2(kr * f.x + ki * f.y, kr * f.y - ki * f.x);
      FkF[idx] = kf;
      bufA[c][u] = kf;
    }
    __syncthreads();
    {
      int u0 = t & 127, p = t >> 7;
      double s1 = 0.0, s2 = 0.0;
#pragma unroll
      for (int s = 0; s < 4; ++s) {
        int u = u0 + ((s & 1) << 7);
        int c = p + ((s >> 1) << 1);
        int gc = j0 + (c & 1) + ((c >> 1) << 7);
        size_t idx = (size_t)n * HWSZ + (size_t)u * NSZ + gc;
        double kr = fkr[idx], ki = fki[idx];
        double k2 = kr * kr + ki * ki;
        double fd2 = fdval(tw, u) + fdval(tw, gc) + 1e-8;
        s1 += k2;
        s2 += k2 / fd2;
      }
      denq[(size_t)n * 16384 + (size_t)u0 * 128 + (j0 + p)] = (float)(s2 * 0.25 + 1e-6);
      dsA[p][u0] = (float)(s1 * 0.25 + 1e-6);
    }
    __syncthreads();
#pragma unroll
    for (int c = 0; c < 4; ++c) {
      int u = t;
      float d = dsA[c & 1][u & 127];
      float2 kf = bufA[c][u];
      bufA[c][u] = make_float2(kf.x / d, kf.y / d);
    }
    fft256(bufA[w], bufB[w], tw, lane, +1.f);
    float2* WFn = WF + (size_t)n * HWSZ;
#pragma unroll
    for (int q = 0; q < 4; ++q) { int u = lane + (q << 6); WFn[(size_t)u * NSZ + gcw] = bufA[w][u]; }
  }
  isync(flags, fbase, sr, ++gen);

  // ---------------- main loop ----------------
  for (int k = 0; k < 50; ++k) {
    // ===== phase A: row inv FFT (6 rows incl halos) + shrink + G + row fwd FFT =====
    float gamp = (k >= 1) ? (float)(0.1 * exp2(-(double)(k - 1) / 50.0)) : 0.f;
    const float *D1p, *D2p; float *D1w, *D2w;
    if (k & 1) { D1p = D1a; D2p = D2a; D1w = D1b; D2w = D2b; }
    else       { D1p = D1b; D2p = D2b; D1w = D1a; D2w = D2a; }

    {
      // batch 1: rows e=0..3 (global rows r0-1 .. r0+2)
      int gr = (r0 + w - 1) & 255;
      const float2* srcW = WF + (size_t)n * HWSZ + (size_t)gr * NSZ;
#pragma unroll
      for (int q = 0; q < 4; ++q) { int j = lane + (q << 6); bufA[w][j] = srcW[j]; }
      fft256(bufA[w], bufB[w], tw, lane, +1.f);
    }
    {
      // batch 2: rows e=4,5 (global rows r0+3, r0+4) on waves 0,1
      bool act = (w < 2);
      int e = 4 + (w & 1);
      int gr = (r0 + e - 1) & 255;
      if (act) {
        const float2* srcW = WF + (size_t)n * HWSZ + (size_t)gr * NSZ;
#pragma unroll
        for (int q = 0; q < 4; ++q) { int j = lane + (q << 6); bufA[e][j] = srcW[j]; }
      }
      fft256g(bufA[e], bufB[e], tw, lane, +1.f, act);
    }
    // shrink rows e=1..5 (global rows r0..r0+4); write D for e=1..4
    for (int e = 1; e <= 5; ++e) {
      int gr = (r0 + e - 1) & 255;
      int j = t, jm1 = (j - 1) & 255;
      float xc = bufA[e][j].x * sc;
      size_t idx = (size_t)n * HWSZ + (size_t)gr * NSZ + j;
      if (k == 49 && e <= 4) x49[idx] = xc;
      float a, b;
      if (k == 0) {
        a = xc; b = xc;
      } else {
        float xl = bufA[e][jm1].x * sc;
        float xu = bufA[e - 1][j].x * sc;
        float dhr = xc - xl;
        float dvr = xc - xu;
        float d1 = D1p[idx], d2 = D2p[idx];
        float nu1 = dhr + d1, nu2 = dvr + d2;
        float nu = sqrtf(nu1 * nu1 + nu2 * nu2 + 1e-8f);
        float A = fmaxf(0.f, nu - gamp) + 1e-8f;
        A = A / (A + gamp);
        float u1 = A * nu1, u2 = A * nu2;
        float d1v = d1 + dhr - u1;
        float d2v = d2 + dvr - u2;
        if (e <= 4) { D1w[idx] = d1v; D2w[idx] = d2v; }
        a = u1 - d1v; b = u2 - d2v;
      }
      aL[e - 1][j] = a;
      bL[e - 1][j] = b;
    }
    __syncthreads();
    // G rows r0..r0+3 + fwd FFT -> WG
    {
#pragma unroll
      for (int q = 0; q < 4; ++q) {
        int j = lane + (q << 6);
        int jp1 = (j + 1) & 255;
        float g = aL[w][j] - aL[w][jp1] + bL[w][j] - bL[w + 1][j];
        bufA[w][j] = make_float2(g, 0.f);
      }
      fft256(bufA[w], bufB[w], tw, lane, -1.f);
      float2* dst = WG + (size_t)n * HWSZ + (size_t)(r0 + w) * NSZ;
#pragma unroll
      for (int q = 0; q < 4; ++q) { int j = lane + (q << 6); dst[j] = bufA[w][j]; }
    }
    isync(flags, fbase, sr, ++gen);

    // ===== phase B: col fwd FFT + freq pointwise + col inv FFT : WG -> WF =====
    {
      float2* WGn = WG + (size_t)n * HWSZ;
#pragma unroll
      for (int q = 0; q < 4; ++q) { int u = lane + (q << 6); bufA[w][u] = WGn[(size_t)u * NSZ + gcw]; }
      fft256(bufA[w], bufB[w], tw, lane, -1.f);
#pragma unroll
      for (int c = 0; c < 4; ++c) {
        int u = t;
        int gc = j0 + (c & 1) + ((c >> 1) << 7);
        size_t idx = (size_t)n * HWSZ + (size_t)u * NSZ + gc;
        float2 kf = FkF[idx];
        float2 fg = bufA[c][u];
        bufA[c][u] = make_float2(kf.x + 1e-6f * fg.x, kf.y + 1e-6f * fg.y);
      }
      __syncthreads();
      {
        int u0 = t & 127, p = t >> 7;
        double sx = 0.0, sy = 0.0;
#pragma unroll
        for (int s = 0; s < 4; ++s) {
          int u = u0 + ((s & 1) << 7);
          int c = p + ((s >> 1) << 1);
          int gc = j0 + (c & 1) + ((c >> 1) << 7);
          size_t idx = (size_t)n * HWSZ + (size_t)u * NSZ + gc;
          float2 f1 = bufA[c][u];
          double kr = fkr[idx], ki = fki[idx];
          double fd2 = fdval(tw, u) + fdval(tw, gc) + 1e-8;
          sx += (kr * (double)f1.x - ki * (double)f1.y) / fd2;
          sy += (kr * (double)f1.y + ki * (double)f1.x) / fd2;
        }
        Ml[p][u0] = make_double2(sx * 0.25, sy * 0.25);
      }
      __syncthreads();
#pragma unroll
      for (int c = 0; c < 4; ++c) {
        int u = t;
        int gc = j0 + (c & 1) + ((c >> 1) << 7);
        size_t idx = (size_t)n * HWSZ + (size_t)u * NSZ + gc;
        float2 f1 = bufA[c][u];
        double2 m = Ml[c & 1][u & 127];
        double den = (double)denq[(size_t)n * 16384 + (size_t)(u & 127) * 128 + (j0 + (c & 1))];
        double kr = fkr[idx], ki = fki[idx];
        double px = (kr * m.x + ki * m.y) / den;
        double py = (kr * m.y - ki * m.x) / den;
        double fd2 = fdval(tw, u) + fdval(tw, gc) + 1e-8;
        double s2 = 1.0 / (1e-6 * fd2);
        bufA[c][u] = make_float2((float)(((double)f1.x - px) * s2),
                                 (float)(((double)f1.y - py) * s2));
      }
      fft256(bufA[w], bufB[w], tw, lane, +1.f);
      float2* WFn = WF + (size_t)n * HWSZ;
#pragma unroll
      for (int q = 0; q < 4; ++q) { int u = lane + (q << 6); WFn[(size_t)u * NSZ + gcw] = bufA[w][u]; }
    }
    isync(flags, fbase, sr, ++gen);
  }

  // ---------------- C: final row inv FFT + momentum -> out ----------------
  {
    const float2* srcW = WF + (size_t)n * HWSZ + (size_t)(r0 + w) * NSZ;
#pragma unroll
    for (int q = 0; q < 4; ++q) { int j = lane + (q << 6); bufA[w][j] = srcW[j]; }
    fft256(bufA[w], bufB[w], tw, lane, +1.f);
    size_t base = (size_t)n * HWSZ + (size_t)(r0 + w) * NSZ;
#pragma unroll
    for (int q = 0; q < 4; ++q) {
      int j = lane + (q << 6);
      float v = bufA[w][j].x * sc;
      out[base + j] = v + cmom * (v - x49[base + j]);
    }
  }
}

// =======================================================================================
//                     FALLBACK: round-0 multi-kernel path (proven correct)
// =======================================================================================
__global__ __launch_bounds__(256) void k_rowfwd_sty(const float* __restrict__ sty,
                                                    float2* __restrict__ Wb)
{
  __shared__ float2 tw[256];
  __shared__ float2 bufA[4][256];
  __shared__ float2 bufB[4][256];
  int t = threadIdx.x;
  make_tw(tw, t);
  int n = blockIdx.x >> 6;
  int r0 = (blockIdx.x & 63) << 2;
  int w = t >> 6, lane = t & 63;
  const float* src = sty + (size_t)n * HWSZ + (size_t)(r0 + w) * NSZ;
#pragma unroll
  for (int q = 0; q < 4; ++q) { int j = lane + (q << 6); bufA[w][j] = make_float2(src[j], 0.f); }
  fft256(bufA[w], bufB[w], tw, lane, -1.f);
  float2* dst = Wb + (size_t)n * HWSZ + (size_t)(r0 + w) * NSZ;
#pragma unroll
  for (int q = 0; q < 4; ++q) { int j = lane + (q << 6); dst[j] = bufA[w][j]; }
}

__global__ __launch_bounds__(256) void k_colsetup(float2* __restrict__ Wb,
                                                  float2* __restrict__ FkF,
                                                  const float* __restrict__ fkr,
                                                  const float* __restrict__ fki,
                                                  float* __restrict__ denq)
{
  __shared__ float2 tw[256];
  __shared__ float2 bufA[4][256];
  __shared__ float2 bufB[4][256];
  __shared__ float dsA[2][128];
  int t = threadIdx.x;
  make_tw(tw, t);
  int n = blockIdx.x >> 6;
  int j0 = (blockIdx.x & 63) << 1;
  int w = t >> 6, lane = t & 63;
  int gcw = j0 + (w & 1) + ((w >> 1) << 7);
  float2* Wn = Wb + (size_t)n * HWSZ;
#pragma unroll
  for (int q = 0; q < 4; ++q) { int u = lane + (q << 6); bufA[w][u] = Wn[(size_t)u * NSZ + gcw]; }
  fft256(bufA[w], bufB[w], tw, lane, -1.f);
#pragma unroll
  for (int c = 0; c < 4; ++c) {
    int u = t;
    int gc = j0 + (c & 1) + ((c >> 1) << 7);
    size_t idx = (size_t)n * HWSZ + (size_t)u * NSZ + gc;
    float kr = fkr[idx], ki = fki[idx];
    float2 f = bufA[c][u];
    float2 kf = make_float2(kr * f.x + ki * f.y, kr * f.y - ki * f.x);
    FkF[idx] = kf;
    bufA[c][u] = kf;
  }
  __syncthreads();
  {
    int u0 = t & 127, p = t >> 7;
    double s1 = 0.0, s2 = 0.0;
#pragma unroll
    for (int s = 0; s < 4; ++s) {
      int u = u0 + ((s & 1) << 7);
      int c = p + ((s >> 1) << 1);
      int gc = j0 + (c & 1) + ((c >> 1) << 7);
      size_t idx = (size_t)n * HWSZ + (size_t)u * NSZ + gc;
      double kr = fkr[idx], ki = fki[idx];
      double k2 = kr * kr + ki * ki;
      double fd2 = fdval(tw, u) + fdval(tw, gc) + 1e-8;
      s1 += k2;
      s2 += k2 / fd2;
    }
    denq[(size_t)n * 16384 + (size_t)u0 * 128 + (j0 + p)] = (float)(s2 * 0.25 + 1e-6);
    dsA[p][u0] = (float)(s1 * 0.25 + 1e-6);
  }
  __syncthreads();
#pragma unroll
  for (int c = 0; c < 4; ++c) {
    int u = t;
    float d = dsA[c & 1][u & 127];
    float2 kf = bufA[c][u];
    bufA[c][u] = make_float2(kf.x / d, kf.y / d);
  }
  fft256(bufA[w], bufB[w], tw, lane, +1.f);
#pragma unroll
  for (int q = 0; q < 4; ++q) { int u = lane + (q << 6); Wn[(size_t)u * NSZ + gcw] = bufA[w][u]; }
}

__global__ __launch_bounds__(256) void k_spatial_rowfwd(const float* __restrict__ x,
                                                        const float* __restrict__ D1p,
                                                        const float* __restrict__ D2p,
                                                        float* __restrict__ D1n,
                                                        float* __restrict__ D2n,
                                                        float2* __restrict__ Wb,
                                                        float gamp, int firstIter)
{
  __shared__ float2 tw[256];
  __shared__ float aL[5][256];
  __shared__ float bL[5][256];
  __shared__ float2 bufA[4][256];
  __shared__ float2 bufB[4][256];
  int t = threadIdx.x;
  make_tw(tw, t);
  int n = blockIdx.x >> 6;
  int r0 = (blockIdx.x & 63) << 2;
  const float* xn = x + (size_t)n * HWSZ;
  for (int rr = 0; rr < 5; ++rr) {
    int i = (r0 + rr) & 255;
    int im1 = (i - 1) & 255;
    int j = t;
    int jm1 = (j - 1) & 255;
    float xc = xn[(size_t)i * NSZ + j];
    float a, b;
    if (firstIter) {
      a = xc; b = xc;
    } else {
      float dhr = xc - xn[(size_t)i * NSZ + jm1];
      float dvr = xc - xn[(size_t)im1 * NSZ + j];
      size_t idx = (size_t)n * HWSZ + (size_t)i * NSZ + j;
      float d1 = D1p[idx], d2 = D2p[idx];
      float nu1 = dhr + d1, nu2 = dvr + d2;
      float nu = sqrtf(nu1 * nu1 + nu2 * nu2 + 1e-8f);
      float A = fmaxf(0.f, nu - gamp) + 1e-8f;
      A = A / (A + gamp);
      float u1 = A * nu1, u2 = A * nu2;
      float d1v = d1 + dhr - u1;
      float d2v = d2 + dvr - u2;
      if (rr < 4) { D1n[idx] = d1v; D2n[idx] = d2v; }
      a = u1 - d1v; b = u2 - d2v;
    }
    aL[rr][j] = a;
    bL[rr][j] = b;
  }
  __syncthreads();
  int w = t >> 6, lane = t & 63;
#pragma unroll
  for (int q = 0; q < 4; ++q) {
    int j = lane + (q << 6);
    int jp1 = (j + 1) & 255;
    float g = aL[w][j] - aL[w][jp1] + bL[w][j] - bL[w + 1][j];
    bufA[w][j] = make_float2(g, 0.f);
  }
  fft256(bufA[w], bufB[w], tw, lane, -1.f);
  float2* dst = Wb + (size_t)n * HWSZ + (size_t)(r0 + w) * NSZ;
#pragma unroll
  for (int q = 0; q < 4; ++q) { int j = lane + (q << 6); dst[j] = bufA[w][j]; }
}

__global__ __launch_bounds__(256) void k_colphase(float2* __restrict__ Wb,
                                                  const float2* __restrict__ FkF,
                                                  const float* __restrict__ fkr,
                                                  const float* __restrict__ fki,
                                                  const float* __restrict__ denq)
{
  __shared__ float2 tw[256];
  __shared__ float2 bufA[4][256];
  __shared__ float2 bufB[4][256];
  __shared__ double2 Ml[2][128];
  int t = threadIdx.x;
  make_tw(tw, t);
  int n = blockIdx.x >> 6;
  int j0 = (blockIdx.x & 63) << 1;
  int w = t >> 6, lane = t & 63;
  int gcw = j0 + (w & 1) + ((w >> 1) << 7);
  float2* Wn = Wb + (size_t)n * HWSZ;
#pragma unroll
  for (int q = 0; q < 4; ++q) { int u = lane + (q << 6); bufA[w][u] = Wn[(size_t)u * NSZ + gcw]; }
  fft256(bufA[w], bufB[w], tw, lane, -1.f);
#pragma unroll
  for (int c = 0; c < 4; ++c) {
    int u = t;
    int gc = j0 + (c & 1) + ((c >> 1) << 7);
    size_t idx = (size_t)n * HWSZ + (size_t)u * NSZ + gc;
    float2 kf = FkF[idx];
    float2 fg = bufA[c][u];
    bufA[c][u] = make_float2(kf.x + 1e-6f * fg.x, kf.y + 1e-6f * fg.y);
  }
  __syncthreads();
  {
    int u0 = t & 127, p = t >> 7;
    double sx = 0.0, sy = 0.0;
#pragma unroll
    for (int s = 0; s < 4; ++s) {
      int u = u0 + ((s & 1) << 7);
      int c = p + ((s >> 1) << 1);
      int gc = j0 + (c & 1) + ((c >> 1) << 7);
      size_t idx = (size_t)n * HWSZ + (size_t)u * NSZ + gc;
      float2 f1 = bufA[c][u];
      double kr = fkr[idx], ki = fki[idx];
      double fd2 = fdval(tw, u) + fdval(tw, gc) + 1e-8;
      sx += (kr * (double)f1.x - ki * (double)f1.y) / fd2;
      sy += (kr * (double)f1.y + ki * (double)f1.x) / fd2;
    }
    Ml[p][u0] = make_double2(sx * 0.25, sy * 0.25);
  }
  __syncthreads();
#pragma unroll
  for (int c = 0; c < 4; ++c) {
    int u = t;
    int gc = j0 + (c & 1) + ((c >> 1) << 7);
    size_t idx = (size_t)n * HWSZ + (size_t)u * NSZ + gc;
    float2 f1 = bufA[c][u];
    double2 m = Ml[c & 1][u & 127];
    double den = (double)denq[(size_t)n * 16384 + (size_t)(u & 127) * 128 + (j0 + (c & 1))];
    double kr = fkr[idx], ki = fki[idx];
    double px = (kr * m.x + ki * m.y) / den;
    double py = (kr * m.y - ki * m.x) / den;
    double fd2 = fdval(tw, u) + fdval(tw, gc) + 1e-8;
    double s2 = 1.0 / (1e-6 * fd2);
    bufA[c][u] = make_float2((float)(((double)f1.x - px) * s2),
                             (float)(((double)f1.y - py) * s2));
  }
  fft256(bufA[w], bufB[w], tw, lane, +1.f);
#pragma unroll
  for (int q = 0; q < 4; ++q) { int u = lane + (q << 6); Wn[(size_t)u * NSZ + gcw] = bufA[w][u]; }
}

__global__ __launch_bounds__(256) void k_rowinv(const float2* __restrict__ Wb,
                                                float* __restrict__ xout,
                                                const float* __restrict__ xold,
                                                float* __restrict__ pred,
                                                float cmom, int isLast)
{
  __shared__ float2 tw[256];
  __shared__ float2 bufA[4][256];
  __shared__ float2 bufB[4][256];
  int t = threadIdx.x;
  make_tw(tw, t);
  int n = blockIdx.x >> 6;
  int r0 = (blockIdx.x & 63) << 2;
  int w = t >> 6, lane = t & 63;
  const float2* src = Wb + (size_t)n * HWSZ + (size_t)(r0 + w) * NSZ;
#pragma unroll
  for (int q = 0; q < 4; ++q) { int j = lane + (q << 6); bufA[w][j] = src[j]; }
  fft256(bufA[w], bufB[w], tw, lane, +1.f);
  size_t base = (size_t)n * HWSZ + (size_t)(r0 + w) * NSZ;
#pragma unroll
  for (int q = 0; q < 4; ++q) {
    int j = lane + (q << 6);
    float v = bufA[w][j].x * (1.0f / 65536.0f);
    xout[base + j] = v;
    if (isLast) pred[base + j] = v + cmom * (v - xold[base + j]);
  }
}

// =======================================================================================
extern "C" void kernel_launch(void* const* d_in, const int* in_sizes, int n_in,
                              void* d_out, int out_size, void* d_ws, size_t ws_size,
                              hipStream_t stream)
{
  (void)in_sizes; (void)n_in; (void)out_size; (void)ws_size;
  const float* STy = (const float*)d_in[0];
  const float* fkr = (const float*)d_in[1];
  const float* fki = (const float*)d_in[2];
  float* out = (float*)d_out;

  char* p = (char*)d_ws;
  const size_t cplx = (size_t)NIMG * HWSZ * sizeof(float2);
  const size_t realb = (size_t)NIMG * HWSZ * sizeof(float);
  float2* WG  = (float2*)p; p += cplx;
  float2* WF  = (float2*)p; p += cplx;
  float2* FkF = (float2*)p; p += cplx;
  float* denq = (float*)p;  p += (size_t)NIMG * 16384 * sizeof(float);
  float* D1a = (float*)p;   p += realb;
  float* D2a = (float*)p;   p += realb;
  float* D1b = (float*)p;   p += realb;
  float* D2b = (float*)p;   p += realb;
  float* xA  = (float*)p;   p += realb;   // mega: x49 ; fallback: x0
  float* xB  = (float*)p;   p += realb;   // fallback: x1
  unsigned* flags = (unsigned*)p; p += 4096;

  // host-side FISTA t sequence -> final momentum coefficient
  double t_old = 1.0, cm = 0.0;
  for (int k = 0; k < 50; ++k) {
    double t_new = (1.0 + sqrt(1.0 + 4.0 * t_old * t_old)) * 0.5;
    if (k == 49) cm = (t_old - 1.0) / t_new;
    t_old = t_new;
  }

  int maxb = 0;
  hipError_t oe = hipOccupancyMaxActiveBlocksPerMultiprocessor(&maxb, k_mega, 256, 0);
  bool coop = (oe == hipSuccess && maxb >= 3);

  hipMemsetAsync(D1a, 0, 2 * realb, stream);   // D^0 = 0

  dim3 grid(NBLK), blk(256);
  if (coop) {
    hipMemsetAsync(flags, 0, 4096, stream);    // poison-proof: must be < first gen
    k_mega<<<grid, blk, 0, stream>>>(STy, fkr, fki, WG, WF, FkF, denq,
                                     D1a, D2a, D1b, D2b, xA, out, (float)cm, flags);
  } else {
    // proven round-0 path
    float2* Wb = WG;
    float* x0 = xA; float* x1 = xB;
    k_rowfwd_sty<<<grid, blk, 0, stream>>>(STy, Wb);
    k_colsetup<<<grid, blk, 0, stream>>>(Wb, FkF, fkr, fki, denq);
    k_rowinv<<<grid, blk, 0, stream>>>(Wb, x0, x0, out, 0.f, 0);
    double to = 1.0;
    for (int k = 0; k < 50; ++k) {
      float gamp = (k >= 1) ? (float)(0.1 * exp2(-(double)(k - 1) / 50.0)) : 0.f;
      const float* xk = (k & 1) ? x1 : x0;
      float* xn = (k & 1) ? x0 : x1;
      const float* D1p = (k & 1) ? D1a : D1b;
      const float* D2p = (k & 1) ? D2a : D2b;
      float* D1w = (k & 1) ? D1b : D1a;
      float* D2w = (k & 1) ? D2b : D2a;
      k_spatial_rowfwd<<<grid, blk, 0, stream>>>(xk, D1p, D2p, D1w, D2w, Wb, gamp, (k == 0) ? 1 : 0);
      k_colphase<<<grid, blk, 0, stream>>>(Wb, FkF, fkr, fki, denq);
      double tn = (1.0 + sqrt(1.0 + 4.0 * to * to)) * 0.5;
      int isLast = (k == 49) ? 1 : 0;
      float cmom = (float)((to - 1.0) / tn);
      k_rowinv<<<grid, blk, 0, stream>>>(Wb, xn, xk, out, isLast ? cmom : 0.f, isLast);
      to = tn;
    }
  }
}